// Round 2
// baseline (278.670 us; speedup 1.0000x reference)
//
#include <hip/hip_runtime.h>
#include <hip/hip_bf16.h>

// Problem constants (fixed by setup_inputs)
#define BQ   4
#define CQ   2
#define EQ   256
#define LQ   16000
#define WQ   40
#define STEP 20
#define TQ   ((LQ - 1) * STEP + WQ)   // 320020
#define TLF  127                      // owned-frame pitch per block (128 computed, 1 overlap)
#define OWN  (TLF * STEP)             // 2540 owned output samples per block
#define NBX  126                      // 126 * 2540 = 320040 >= 320020

// One block: 256 threads = 2 (c) x 128 (frames). Thread (c, ll) computes
// frame f = 127*bx - 1 + ll: frame[w] = sum_e mix[b,e,f]*mask[b,c,e,f]*basisT[e][w].
// Frames overlap-add into LDS (even/odd phase -> no atomics); block stores the
// disjoint span t in [2540*bx, 2540*bx+2540).
__global__ __launch_bounds__(256) void decoder_kernel(
    const float* __restrict__ mix,    // [B,E,L]
    const float* __restrict__ mask,   // [B,C,E,L]
    const float* __restrict__ basis,  // [W,E]
    float* __restrict__ out)          // [B,C,T]
{
    __shared__ __align__(16) float basisT[EQ * WQ];          // [e][w], 40 KB
    __shared__ float outS[CQ][TLF * STEP + WQ + STEP];       // 2580 floats per c

    const int tid = threadIdx.x;
    const int c   = tid >> 7;          // 0..1
    const int ll  = tid & 127;         // local frame index
    const int bx  = blockIdx.x;
    const int b   = blockIdx.y;
    const int f   = TLF * bx - 1 + ll; // global frame index (may be out of range)

    // Stage basis transposed into LDS: basisT[e*40 + w] = basis[w*256 + e]
    for (int i = tid; i < EQ * WQ; i += 256) {
        int w = i >> 8;        // i / EQ
        int e = i & (EQ - 1);  // i % EQ
        basisT[e * WQ + w] = basis[i];
    }
    // Zero the LDS tail [2560,2580) that only the odd phase touches.
    if (tid < CQ * STEP) {
        int cc = tid / STEP;
        int i  = tid % STEP;
        outS[cc][TLF * STEP + STEP + i] = 0.0f;
    }
    __syncthreads();

    float acc[WQ];
#pragma unroll
    for (int w = 0; w < WQ; ++w) acc[w] = 0.0f;

    if (f >= 0 && f < LQ) {
        const float* mp = mix  + (size_t)b * EQ * LQ + f;
        const float* kp = mask + (size_t)(b * CQ + c) * EQ * LQ + f;
#pragma unroll 2
        for (int e = 0; e < EQ; ++e) {
            float m = *mp;
            float k = *kp;
            mp += LQ;
            kp += LQ;
            float s = m * k;
            const float4* bt = (const float4*)(&basisT[e * WQ]);
#pragma unroll
            for (int j = 0; j < WQ / 4; ++j) {
                float4 bv = bt[j];
                acc[4 * j + 0] = fmaf(s, bv.x, acc[4 * j + 0]);
                acc[4 * j + 1] = fmaf(s, bv.y, acc[4 * j + 1]);
                acc[4 * j + 2] = fmaf(s, bv.z, acc[4 * j + 2]);
                acc[4 * j + 3] = fmaf(s, bv.w, acc[4 * j + 3]);
            }
        }
    }

    // Overlap-add into LDS. Even ll ranges [20*ll, 20*ll+40) tile [0,2560)
    // exactly once -> plain store; odd ll then accumulates.
    const int base = ll * STEP;
    if ((ll & 1) == 0) {
#pragma unroll
        for (int w = 0; w < WQ; ++w) outS[c][base + w] = acc[w];
    }
    __syncthreads();
    if (ll & 1) {
#pragma unroll
        for (int w = 0; w < WQ; ++w) outS[c][base + w] += acc[w];
    }
    __syncthreads();

    // Store the owned span: t = 2540*bx + i  <->  outS[c][20 + i], i in [0,2540)
    for (int cc = 0; cc < CQ; ++cc) {
        const size_t ob = ((size_t)b * CQ + cc) * TQ + (size_t)OWN * bx;
        for (int i = tid; i < OWN; i += 256) {
            const long t = (long)OWN * bx + i;
            if (t < (long)TQ) {
                out[ob + i] = outS[cc][STEP + i];
            }
        }
    }
}

extern "C" void kernel_launch(void* const* d_in, const int* in_sizes, int n_in,
                              void* d_out, int out_size, void* d_ws, size_t ws_size,
                              hipStream_t stream) {
    const float* mix   = (const float*)d_in[0];
    const float* mask  = (const float*)d_in[1];
    const float* basis = (const float*)d_in[2];
    float* out = (float*)d_out;

    dim3 grid(NBX, BQ);
    decoder_kernel<<<grid, 256, 0, stream>>>(mix, mask, basis, out);
}

// Round 3
// 243.129 us; speedup vs baseline: 1.1462x; 1.1462x over previous
//
#include <hip/hip_runtime.h>
#include <hip/hip_bf16.h>

// Problem constants (fixed by setup_inputs)
#define BQ   4
#define CQ   2
#define EQ   256
#define LQ   16000
#define WQ   40
#define STEP 20
#define TQ   ((LQ - 1) * STEP + WQ)   // 320020
#define TLF  127                      // owned-frame pitch per block (128 computed, 1 overlap)
#define OWN  (TLF * STEP)             // 2540 owned output samples per block
#define NBX  126                      // 126 * 2540 = 320040 >= 320020
#define EH   (EQ / 2)                 // e-chunk per thread (halved chain for MLP)

// One block: 512 threads = 2 e-halves (h) x 2 channels (c) x 128 frames (ll).
// Thread (h,c,ll) computes the partial frame over e in [h*128,(h+1)*128):
//   part[w] = sum_e mix[b,e,f] * mask[b,c,e,f] * basisT[e][w],  f = 127*bx-1+ll.
// Overlap-add into LDS in 4 serialized phases (even/odd ll x h) -> no atomics.
// Block stores the disjoint span t in [2540*bx, 2540*bx+2540).
__global__ __launch_bounds__(512, 4) void decoder_kernel(
    const float* __restrict__ mix,    // [B,E,L]
    const float* __restrict__ mask,   // [B,C,E,L]
    const float* __restrict__ basis,  // [W,E]
    float* __restrict__ out)          // [B,C,T]
{
    __shared__ __align__(16) float basisT[EQ * WQ];          // [e][w], 40 KB
    __shared__ float outS[CQ][TLF * STEP + WQ + STEP];       // 2580 floats per c

    const int tid = threadIdx.x;
    const int ll  = tid & 127;         // local frame index
    const int c   = (tid >> 7) & 1;    // channel
    const int h   = tid >> 8;          // e-half
    const int bx  = blockIdx.x;
    const int b   = blockIdx.y;
    const int f   = TLF * bx - 1 + ll; // global frame index (may be out of range)

    // Stage basis transposed into LDS: basisT[e*40 + w] = basis[w*256 + e]
    for (int i = tid; i < EQ * WQ; i += 512) {
        int w = i >> 8;        // i / EQ
        int e = i & (EQ - 1);  // i % EQ
        basisT[e * WQ + w] = basis[i];
    }
    // Zero the LDS tail [2560,2580) that only the odd phases touch.
    if (tid < CQ * STEP) {
        int cc = tid / STEP;
        int i  = tid % STEP;
        outS[cc][TLF * STEP + STEP + i] = 0.0f;
    }
    __syncthreads();

    float acc[WQ];
#pragma unroll
    for (int w = 0; w < WQ; ++w) acc[w] = 0.0f;

    if (f >= 0 && f < LQ) {
        const float* mp = mix  + ((size_t)b * EQ + h * EH) * LQ + f;
        const float* kp = mask + (((size_t)(b * CQ + c)) * EQ + h * EH) * LQ + f;
        const float* bt0 = &basisT[(h * EH) * WQ];
        for (int eo = 0; eo < EH; eo += 4) {
            float m[4], k[4];
#pragma unroll
            for (int u = 0; u < 4; ++u) {
                m[u] = mp[(size_t)(eo + u) * LQ];
                k[u] = kp[(size_t)(eo + u) * LQ];
            }
#pragma unroll
            for (int u = 0; u < 4; ++u) {
                float s = m[u] * k[u];
                const float4* bt = (const float4*)(bt0 + (eo + u) * WQ);
#pragma unroll
                for (int j = 0; j < WQ / 4; ++j) {
                    float4 bv = bt[j];
                    acc[4 * j + 0] = fmaf(s, bv.x, acc[4 * j + 0]);
                    acc[4 * j + 1] = fmaf(s, bv.y, acc[4 * j + 1]);
                    acc[4 * j + 2] = fmaf(s, bv.z, acc[4 * j + 2]);
                    acc[4 * j + 3] = fmaf(s, bv.w, acc[4 * j + 3]);
                }
            }
        }
    }

    // Overlap-add into LDS, 4 serialized phases. Within a phase, the ranges
    // [20*ll, 20*ll+40) for ll of one parity are mutually disjoint.
    const int base = ll * STEP;
    if (h == 0 && (ll & 1) == 0) {
#pragma unroll
        for (int w = 0; w < WQ; ++w) outS[c][base + w] = acc[w];
    }
    __syncthreads();
    if (h == 0 && (ll & 1)) {
#pragma unroll
        for (int w = 0; w < WQ; ++w) outS[c][base + w] += acc[w];
    }
    __syncthreads();
    if (h == 1 && (ll & 1) == 0) {
#pragma unroll
        for (int w = 0; w < WQ; ++w) outS[c][base + w] += acc[w];
    }
    __syncthreads();
    if (h == 1 && (ll & 1)) {
#pragma unroll
        for (int w = 0; w < WQ; ++w) outS[c][base + w] += acc[w];
    }
    __syncthreads();

    // Store the owned span: t = 2540*bx + i  <->  outS[c][20 + i], i in [0,2540)
    for (int cc = 0; cc < CQ; ++cc) {
        const size_t ob = ((size_t)b * CQ + cc) * TQ + (size_t)OWN * bx;
        for (int i = tid; i < OWN; i += 512) {
            const long t = (long)OWN * bx + i;
            if (t < (long)TQ) {
                out[ob + i] = outS[cc][STEP + i];
            }
        }
    }
}

extern "C" void kernel_launch(void* const* d_in, const int* in_sizes, int n_in,
                              void* d_out, int out_size, void* d_ws, size_t ws_size,
                              hipStream_t stream) {
    const float* mix   = (const float*)d_in[0];
    const float* mask  = (const float*)d_in[1];
    const float* basis = (const float*)d_in[2];
    float* out = (float*)d_out;

    dim3 grid(NBX, BQ);
    decoder_kernel<<<grid, 512, 0, stream>>>(mix, mask, basis, out);
}

// Round 4
// 242.735 us; speedup vs baseline: 1.1480x; 1.0016x over previous
//
#include <hip/hip_runtime.h>

// Problem constants (fixed by setup_inputs)
#define BQ   4
#define CQ   2
#define EQ   256
#define LQ   16000
#define WQ   40
#define STEP 20
#define TQ   ((LQ - 1) * STEP + WQ)   // 320020
#define TLF  63                       // owned-frame pitch per block (64 computed, 1 overlap)
#define OWN  (TLF * STEP)             // 1260 owned output samples per block
#define NBX  254                      // 254 * 1260 = 320040 >= 320020
#define NH   4                        // e-quarters
#define EH   (EQ / NH)                // 64 e's per thread
#define SPAN (TLF * STEP + WQ + STEP) // 1320 floats per (copy, c)

// Pre-kernel: transpose basis [W][E] -> wsT [E][W] (fp32, rows contiguous)
// so the main loop can read each e-row with wave-uniform scalar loads.
__global__ void transpose_basis_kernel(const float* __restrict__ basis,
                                       float* __restrict__ wsT) {
    int i = blockIdx.x * 256 + threadIdx.x;
    if (i < EQ * WQ) {
        int e = i / WQ;
        int w = i - e * WQ;
        wsT[i] = basis[w * EQ + e];
    }
}

// One block: 512 threads = 4 e-quarters (h) x 2 channels (c) x 64 frames (ll).
// Thread (h,c,ll) computes partial frame f = 63*bx - 1 + ll over e-quarter h:
//   part[w] = sum_e mix[b,e,f]*mask[b,c,e,f]*wsT[e][w]   (wsT row in SGPRs).
// Overlap-add into 2 LDS copies (one per h-pair), 4 serialized parity phases
// -> no atomics. Block stores the disjoint span t in [1260*bx, 1260*bx+1260).
__global__ __launch_bounds__(512, 8) void decoder_kernel(
    const float* __restrict__ mix,    // [B,E,L]
    const float* __restrict__ mask,   // [B,C,E,L]
    const float* __restrict__ wsT,    // [E,W] transposed basis
    float* __restrict__ out)          // [B,C,T]
{
    __shared__ float outS[2][CQ][SPAN];   // ~21 KB

    const int tid = threadIdx.x;
    const int ll  = tid & 63;                                  // frame lane
    const int c   = (tid >> 6) & 1;                            // channel (wave-uniform)
    const int h   = __builtin_amdgcn_readfirstlane(tid >> 7);  // e-quarter, forced uniform
    const int bx  = blockIdx.x;
    const int b   = blockIdx.y;
    const int f   = TLF * bx - 1 + ll;   // may be out of [0,LQ)

    // Clamp + validity multiplier: keeps the K-loop branch-free so the
    // wave-uniform basis loads can be scalarized (no divergent CF).
    const int   fc    = min(max(f, 0), LQ - 1);
    const float valid = (f >= 0 && f < LQ) ? 1.0f : 0.0f;

    float acc[WQ];
#pragma unroll
    for (int w = 0; w < WQ; ++w) acc[w] = 0.0f;

    const float* mp = mix  + ((size_t)b * EQ + h * EH) * LQ + fc;
    const float* kp = mask + (((size_t)(b * CQ + c)) * EQ + h * EH) * LQ + fc;
    const float* bp = wsT + (size_t)h * EH * WQ;   // wave-uniform

    for (int eo = 0; eo < EH; eo += 2) {
        float m0 = mp[(size_t)eo * LQ];
        float m1 = mp[(size_t)(eo + 1) * LQ];
        float k0 = kp[(size_t)eo * LQ] * valid;
        float k1 = kp[(size_t)(eo + 1) * LQ] * valid;
        {
            float s = m0 * k0;
            const float* bb = bp + eo * WQ;        // uniform -> s_load
#pragma unroll
            for (int w = 0; w < WQ; ++w) acc[w] = fmaf(s, bb[w], acc[w]);
        }
        {
            float s = m1 * k1;
            const float* bb = bp + (eo + 1) * WQ;  // uniform -> s_load
#pragma unroll
            for (int w = 0; w < WQ; ++w) acc[w] = fmaf(s, bb[w], acc[w]);
        }
    }

    // Overlap-add into LDS copy cp = h>>1. Within a copy, 4 serialized phases
    // (h-parity x ll-parity); even-ll ranges [20*ll,20*ll+40) tile [0,1280)
    // exactly, so phase 0 is a plain store (no pre-zero needed; indices
    // [1280,1300) are written by odd-ll adds but never read back).
    const int base = ll * STEP;
    const int cp   = h >> 1;
    const int hp   = h & 1;
    if (hp == 0 && (ll & 1) == 0) {
#pragma unroll
        for (int w = 0; w < WQ; ++w) outS[cp][c][base + w] = acc[w];
    }
    __syncthreads();
    if (hp == 0 && (ll & 1) == 1) {
#pragma unroll
        for (int w = 0; w < WQ; ++w) outS[cp][c][base + w] += acc[w];
    }
    __syncthreads();
    if (hp == 1 && (ll & 1) == 0) {
#pragma unroll
        for (int w = 0; w < WQ; ++w) outS[cp][c][base + w] += acc[w];
    }
    __syncthreads();
    if (hp == 1 && (ll & 1) == 1) {
#pragma unroll
        for (int w = 0; w < WQ; ++w) outS[cp][c][base + w] += acc[w];
    }
    __syncthreads();

    // Store owned span: t = 1260*bx + i  <->  outS[*][c][20 + i], i in [0,1260)
    for (int cc = 0; cc < CQ; ++cc) {
        const size_t ob = ((size_t)b * CQ + cc) * TQ + (size_t)OWN * bx;
        for (int i = tid; i < OWN; i += 512) {
            const long t = (long)OWN * bx + i;
            if (t < (long)TQ) {
                out[ob + i] = outS[0][cc][STEP + i] + outS[1][cc][STEP + i];
            }
        }
    }
}

extern "C" void kernel_launch(void* const* d_in, const int* in_sizes, int n_in,
                              void* d_out, int out_size, void* d_ws, size_t ws_size,
                              hipStream_t stream) {
    const float* mix   = (const float*)d_in[0];
    const float* mask  = (const float*)d_in[1];
    const float* basis = (const float*)d_in[2];
    float* out = (float*)d_out;
    float* wsT = (float*)d_ws;   // needs EQ*WQ*4 = 40960 bytes

    transpose_basis_kernel<<<dim3((EQ * WQ + 255) / 256), 256, 0, stream>>>(basis, wsT);

    dim3 grid(NBX, BQ);
    decoder_kernel<<<grid, 512, 0, stream>>>(mix, mask, wsT, out);
}